// Round 2
// baseline (353.783 us; speedup 1.0000x reference)
//
#include <hip/hip_runtime.h>

#define NN     100000
#define DEG    16
#define IN_F   128
#define OUT_F  32
#define KK     4
#define JDIM   (KK * OUT_F)   // 128
#define TRS    70             // transpose-buffer row stride in shorts (pad vs 64)
#define GRIDB  512            // 2 blocks/CU x 256 CU -> all co-resident
#define NTILES ((NN + 31) / 32)   // 3125
#define NGRP   ((NN + 63) / 64)   // 1563

typedef __attribute__((ext_vector_type(8))) short short8;     // 8 bf16 = 4 VGPR
typedef __attribute__((ext_vector_type(4))) short short4v;    // 4 bf16 = 8 B
typedef __attribute__((ext_vector_type(4))) float floatx4;    // MFMA C/D

// fp32 -> bf16 bits, round-to-nearest-even (inputs are finite normals)
static __device__ __forceinline__ unsigned short f2bf(float f) {
  unsigned int u = __builtin_bit_cast(unsigned int, f);
  u += 0x7fffu + ((u >> 16) & 1u);
  return (unsigned short)(u >> 16);
}

// ---------------------------------------------------------------------------
// Fused kernel, PLAIN launch + software grid barrier (cooperative launch was
// rejected by the runtime in round 1 -> all-zero output, NaN timing).
// Residency guarantee for the barrier (skill-sanctioned manual arithmetic):
//   __launch_bounds__(256,2): VGPR capped at 256/wave (live set ~200, no
//   spill) -> 2 blocks/CU; LDS 50688 B -> 160KiB/50688 = 3 blocks/CU;
//   threads 2048/512 = 8 blocks/CU. Min = 2 blocks/CU x 256 CU = 512 = GRIDB.
//   All blocks co-resident on the idle GPU -> spin barrier cannot deadlock.
// Barrier counter lives in d_ws (+26MB); zeroed per launch by a capturable
// hipMemsetAsync node ordered before the kernel.
//   Phase P: fc_w fp32 -> bf16 MFMA A-fragments directly into LDS (per block).
//   Phase A: grid-stride over 32-node tiles; round-7 MFMA body verbatim.
//   barrier (release nf, acquire before gather)
//   Phase B: grid-stride over 64-node groups; round-3 gather verbatim
//            (measured 63-65us, occupancy-invariant 18-52% -> structural).
// ---------------------------------------------------------------------------
__global__ __launch_bounds__(256, 2) void gmm_fused(
    const int* __restrict__ rowptr, const int* __restrict__ colind,
    const int* __restrict__ permute, const float* __restrict__ feat,
    const float* __restrict__ pseudo, const float* __restrict__ fc_w,
    const float* __restrict__ mu, const float* __restrict__ inv_sigma,
    const float* __restrict__ bias, unsigned short* __restrict__ nf,
    unsigned int* __restrict__ barrier_ctr, float* __restrict__ out)
{
  __shared__ __align__(16) char smem[50688];
  uint4* s_wfrag = (uint4*)smem;                                   // 32 KB
  unsigned short* s_tr_base = (unsigned short*)(smem + 32768);     // 17.9 KB

  const int tid  = threadIdx.x;
  const int lane = tid & 63;
  const int wv   = tid >> 6;

  // ---- Phase P: convert W into LDS fragment order (8 slots/thread) ----
#pragma unroll
  for (int r = 0; r < 8; ++r) {
    const int g = r * 256 + tid;                  // 0..2047
    const int c = g & 15, q = (g >> 4) & 3, t = (g >> 6) & 7, s = g >> 9;
    const float* src = fc_w + (size_t)(t * 16 + c) * IN_F + s * 32 + q * 8;
    const float4 f0 = *(const float4*)src;
    const float4 f1 = *(const float4*)(src + 4);
    short8 v;
    v[0] = (short)f2bf(f0.x); v[1] = (short)f2bf(f0.y);
    v[2] = (short)f2bf(f0.z); v[3] = (short)f2bf(f0.w);
    v[4] = (short)f2bf(f1.x); v[5] = (short)f2bf(f1.y);
    v[6] = (short)f2bf(f1.z); v[7] = (short)f2bf(f1.w);
    *(short8*)(s_wfrag + g) = v;
  }
  __syncthreads();

  // ---- Phase A: grid-stride over 32-node tiles, one tile per wave ----
  const short8* wlds = (const short8*)s_wfrag;
  unsigned short* tr = s_tr_base + wv * (32 * TRS);

  for (int tile = blockIdx.x * 4 + wv; tile < NTILES; tile += GRIDB * 4) {
    const int m0 = tile * 32;                    // NN % 32 == 0: full tiles
    const int c  = lane & 15;
    const int q  = lane >> 4;

    // batch-load all feat inputs for this wave (16-deep MLP, one exposure)
    const float* frow0 = feat + (size_t)(m0 + c) * IN_F + q * 8;
    const float* frow1 = frow0 + (size_t)16 * IN_F;
    float4 fr[2][4][2];
#pragma unroll
    for (int s = 0; s < 4; ++s) {
      fr[0][s][0] = *(const float4*)(frow0 + s * 32);
      fr[0][s][1] = *(const float4*)(frow0 + s * 32 + 4);
      fr[1][s][0] = *(const float4*)(frow1 + s * 32);
      fr[1][s][1] = *(const float4*)(frow1 + s * 32 + 4);
    }

    // convert to bf16 B-fragments
    short8 bv[2][4];
#pragma unroll
    for (int g = 0; g < 2; ++g) {
#pragma unroll
      for (int s = 0; s < 4; ++s) {
        const float4 b0 = fr[g][s][0];
        const float4 b1 = fr[g][s][1];
        short8 v;
        v[0] = (short)f2bf(b0.x); v[1] = (short)f2bf(b0.y);
        v[2] = (short)f2bf(b0.z); v[3] = (short)f2bf(b0.w);
        v[4] = (short)f2bf(b1.x); v[5] = (short)f2bf(b1.y);
        v[6] = (short)f2bf(b1.z); v[7] = (short)f2bf(b1.w);
        bv[g][s] = v;
      }
    }

    floatx4 acc[2][8];
#pragma unroll
    for (int g = 0; g < 2; ++g)
#pragma unroll
      for (int t = 0; t < 8; ++t) acc[g][t] = (floatx4){0.f, 0.f, 0.f, 0.f};

#pragma unroll
    for (int s = 0; s < 4; ++s) {
#pragma unroll
      for (int t = 0; t < 8; ++t) {
        const short8 av = wlds[(s * 8 + t) * 64 + lane];
        acc[0][t] = __builtin_amdgcn_mfma_f32_16x16x32_bf16(av, bv[0][s], acc[0][t], 0, 0, 0);
        acc[1][t] = __builtin_amdgcn_mfma_f32_16x16x32_bf16(av, bv[1][s], acc[1][t], 0, 0, 0);
      }
    }

    // Epilogue: two j-halves (th), wave-private transpose buffer.
    // acc[g][t][r] -> node row g*16+c, j = t*16 + q*4 + r.
#pragma unroll
    for (int th = 0; th < 2; ++th) {
#pragma unroll
      for (int g = 0; g < 2; ++g) {
#pragma unroll
        for (int tt = 0; tt < 4; ++tt) {
          const int t = th * 4 + tt;
          short4v p;
          p[0] = (short)f2bf(acc[g][t][0]); p[1] = (short)f2bf(acc[g][t][1]);
          p[2] = (short)f2bf(acc[g][t][2]); p[3] = (short)f2bf(acc[g][t][3]);
          *(short4v*)&tr[(g * 16 + c) * TRS + tt * 16 + q * 4] = p;
        }
      }
      // read back + store: 4 uint4/lane, 8 rows x 128 B contiguous per instr
#pragma unroll
      for (int jj = 0; jj < 4; ++jj) {
        const int chunk = jj * 64 + lane;       // 16 B chunks, 256 total
        const int row = chunk >> 3;             // node row 0..31
        const int co  = chunk & 7;              // chunk within 128 B half-row
        const uint4 v = *(const uint4*)&tr[row * TRS + co * 8];
        *(uint4*)(nf + (size_t)(m0 + row) * JDIM + th * 64 + co * 8) = v;
      }
    }
  }

  // ---- software grid barrier: release nf, arrive, spin, acquire ----
  __threadfence();                 // device-scope release of nf stores
  __syncthreads();                 // whole block arrived
  if (tid == 0) {
    __hip_atomic_fetch_add(barrier_ctr, 1u, __ATOMIC_RELEASE,
                           __HIP_MEMORY_SCOPE_AGENT);
    while (__hip_atomic_load(barrier_ctr, __ATOMIC_ACQUIRE,
                             __HIP_MEMORY_SCOPE_AGENT) < (unsigned)GRIDB)
      __builtin_amdgcn_s_sleep(8);
  }
  __syncthreads();                 // block released together
  __threadfence();                 // acquire side for nf reads

  // ---- Phase B: edge gather (round-3 verbatim), LDS overlaid ----
  int*  s_src = (int*)smem;                        // 4 KB
  float (*s_wB)[4] = (float(*)[4])(smem + 4096);   // 16 KB

  float mx[KK], my[KK], sx[KK], sy[KK];
#pragma unroll
  for (int k = 0; k < KK; ++k) {
    mx[k] = mu[k * 2 + 0];
    my[k] = mu[k * 2 + 1];
    sx[k] = inv_sigma[k * 2 + 0];
    sy[k] = inv_sigma[k * 2 + 1];
  }

  const int nl = tid >> 2;    // local node 0..63
  const int f8 = tid & 3;     // features f8*8 .. f8*8+7

  for (int grp = blockIdx.x; grp < NGRP; grp += GRIDB) {
    __syncthreads();          // previous round's readers done before restage
    const int node0  = grp * 64;
    const int nvalid = (NN - node0 < 64) ? (NN - node0) : 64;

    // stage 1024 edges (4 per thread): src id + 4 gaussian weights
#pragma unroll
    for (int r = 0; r < 4; ++r) {
      const int t  = tid + r * 256;
      const int nle = t >> 4;
      if (nle < nvalid) {
        const int e   = rowptr[node0 + nle] + (t & 15);
        const int pe  = permute[e];
        s_src[t] = colind[e];
        const float px = pseudo[(size_t)pe * 2 + 0];
        const float py = pseudo[(size_t)pe * 2 + 1];
#pragma unroll
        for (int k = 0; k < KK; ++k) {
          const float dx = (px - mx[k]) * sx[k];
          const float dy = (py - my[k]) * sy[k];
          s_wB[t][k] = __expf(-0.5f * (dx * dx + dy * dy));
        }
      }
    }
    __syncthreads();

    if (nl < nvalid) {
      float acc[8];
      {
        const float4 b0 = *(const float4*)&bias[f8 * 8];
        const float4 b1 = *(const float4*)&bias[f8 * 8 + 4];
        acc[0] = b0.x; acc[1] = b0.y; acc[2] = b0.z; acc[3] = b0.w;
        acc[4] = b1.x; acc[5] = b1.y; acc[6] = b1.z; acc[7] = b1.w;
      }

      const int tbase = nl * 16;
#pragma unroll
      for (int i = 0; i < DEG; ++i) {
        const int e = (i + nl) & 15;          // rotate: conflict-free LDS reads
        const int t = tbase + e;
        const int src = s_src[t];
        const float4 w4 = *(const float4*)&s_wB[t][0];
        const float wvv[4] = {w4.x, w4.y, w4.z, w4.w};
        const unsigned short* row = nf + (size_t)src * JDIM + f8 * 8;
#pragma unroll
        for (int k = 0; k < KK; ++k) {
          const uint4 v = *(const uint4*)(row + k * 32);
          const float wk = wvv[k];
          acc[0] += wk * __uint_as_float(v.x << 16);
          acc[1] += wk * __uint_as_float(v.x & 0xffff0000u);
          acc[2] += wk * __uint_as_float(v.y << 16);
          acc[3] += wk * __uint_as_float(v.y & 0xffff0000u);
          acc[4] += wk * __uint_as_float(v.z << 16);
          acc[5] += wk * __uint_as_float(v.z & 0xffff0000u);
          acc[6] += wk * __uint_as_float(v.w << 16);
          acc[7] += wk * __uint_as_float(v.w & 0xffff0000u);
        }
      }

      float4 o0 = {acc[0], acc[1], acc[2], acc[3]};
      float4 o1 = {acc[4], acc[5], acc[6], acc[7]};
      float* op = out + (size_t)(node0 + nl) * OUT_F + f8 * 8;
      *(float4*)(op)     = o0;
      *(float4*)(op + 4) = o1;
    }
  }
}

extern "C" void kernel_launch(void* const* d_in, const int* in_sizes, int n_in,
                              void* d_out, int out_size, void* d_ws, size_t ws_size,
                              hipStream_t stream) {
  const int*   rowptr    = (const int*)d_in[0];
  const int*   colind    = (const int*)d_in[1];
  // d_in[2] colptr, d_in[3] rowind: backward-only, unused in fwd
  const int*   permute   = (const int*)d_in[4];
  const float* feat      = (const float*)d_in[5];
  const float* pseudo    = (const float*)d_in[6];
  const float* fc_w      = (const float*)d_in[7];
  const float* mu        = (const float*)d_in[8];
  const float* inv_sigma = (const float*)d_in[9];
  const float* bias      = (const float*)d_in[10];
  float* out = (float*)d_out;

  unsigned short* nf = (unsigned short*)d_ws;                       // 25.6 MB
  unsigned int* barrier_ctr = (unsigned int*)((char*)d_ws + (26u << 20));

  // zero the barrier counter every launch (capturable async node)
  hipMemsetAsync(barrier_ctr, 0, sizeof(unsigned int), stream);

  gmm_fused<<<GRIDB, 256, 0, stream>>>(
      rowptr, colind, permute, feat, pseudo, fc_w, mu, inv_sigma,
      bias, nf, barrier_ctr, out);
}

// Round 3
// 203.069 us; speedup vs baseline: 1.7422x; 1.7422x over previous
//
#include <hip/hip_runtime.h>

#define NN     100000
#define DEG    16
#define IN_F   128
#define OUT_F  32
#define KK     4
#define JDIM   (KK * OUT_F)   // 128
#define TRS    70             // transpose-buffer row stride in shorts (pad vs 64)
#define NTILES ((NN + 31) / 32)   // 3125

typedef __attribute__((ext_vector_type(8))) short short8;     // 8 bf16 = 4 VGPR
typedef __attribute__((ext_vector_type(4))) short short4v;    // 4 bf16 = 8 B
typedef __attribute__((ext_vector_type(4))) float floatx4;    // MFMA C/D

// fp32 -> bf16 bits, round-to-nearest-even (inputs are finite normals)
static __device__ __forceinline__ unsigned short f2bf(float f) {
  unsigned int u = __builtin_bit_cast(unsigned int, f);
  u += 0x7fffu + ((u >> 16) & 1u);
  return (unsigned short)(u >> 16);
}

// ---------------------------------------------------------------------------
// Kernel A (MFMA), round-7 structure verbatim + P folded inline:
// each block converts fc_w (fp32, L2-resident 64 KB) -> bf16 MFMA A-fragments
// directly into LDS (slot g=(s*8+t)*64+q*16+c holds fc_w[t*16+c][s*32+q*8..+7]),
// saving the separate gmm_cvt_w dispatch and the wcvt global round-trip.
// One wave per 32-node tile, 4 waves/block, wave-private LDS-transpose
// epilogue for 128 B-contiguous nf stores. LDS 49.5 KB -> 3 blocks/CU.
// ---------------------------------------------------------------------------
__global__ __launch_bounds__(256) void gmm_fc_mfma(
    const float* __restrict__ feat, const float* __restrict__ fc_w,
    unsigned short* __restrict__ nf)
{
  __shared__ uint4 s_wfrag[2048];                    // 32 KB
  __shared__ unsigned short s_tr[4][32 * TRS];       // 4 x 4.4 KB

  const int tid  = threadIdx.x;
  const int lane = tid & 63;
  const int wv   = tid >> 6;

  // inline W conversion: 8 fragment slots per thread, straight into LDS
#pragma unroll
  for (int r = 0; r < 8; ++r) {
    const int g = r * 256 + tid;                  // 0..2047
    const int c = g & 15, q = (g >> 4) & 3, t = (g >> 6) & 7, s = g >> 9;
    const float* src = fc_w + (size_t)(t * 16 + c) * IN_F + s * 32 + q * 8;
    const float4 f0 = *(const float4*)src;
    const float4 f1 = *(const float4*)(src + 4);
    short8 v;
    v[0] = (short)f2bf(f0.x); v[1] = (short)f2bf(f0.y);
    v[2] = (short)f2bf(f0.z); v[3] = (short)f2bf(f0.w);
    v[4] = (short)f2bf(f1.x); v[5] = (short)f2bf(f1.y);
    v[6] = (short)f2bf(f1.z); v[7] = (short)f2bf(f1.w);
    *(short8*)&s_wfrag[g] = v;
  }
  __syncthreads();

  const int tile = blockIdx.x * 4 + wv;            // 32-node tile id
  if (tile * 32 >= NN) return;                     // NN % 32 == 0: full tiles
  const int m0 = tile * 32;
  const int c  = lane & 15;
  const int q  = lane >> 4;

  // batch-load all feat inputs for this wave (16-deep MLP, one exposure)
  const float* frow0 = feat + (size_t)(m0 + c) * IN_F + q * 8;
  const float* frow1 = frow0 + (size_t)16 * IN_F;
  float4 fr[2][4][2];
#pragma unroll
  for (int s = 0; s < 4; ++s) {
    fr[0][s][0] = *(const float4*)(frow0 + s * 32);
    fr[0][s][1] = *(const float4*)(frow0 + s * 32 + 4);
    fr[1][s][0] = *(const float4*)(frow1 + s * 32);
    fr[1][s][1] = *(const float4*)(frow1 + s * 32 + 4);
  }

  // convert to bf16 B-fragments
  short8 bv[2][4];
#pragma unroll
  for (int g = 0; g < 2; ++g) {
#pragma unroll
    for (int s = 0; s < 4; ++s) {
      const float4 b0 = fr[g][s][0];
      const float4 b1 = fr[g][s][1];
      short8 v;
      v[0] = (short)f2bf(b0.x); v[1] = (short)f2bf(b0.y);
      v[2] = (short)f2bf(b0.z); v[3] = (short)f2bf(b0.w);
      v[4] = (short)f2bf(b1.x); v[5] = (short)f2bf(b1.y);
      v[6] = (short)f2bf(b1.z); v[7] = (short)f2bf(b1.w);
      bv[g][s] = v;
    }
  }

  floatx4 acc[2][8];
#pragma unroll
  for (int g = 0; g < 2; ++g)
#pragma unroll
    for (int t = 0; t < 8; ++t) acc[g][t] = (floatx4){0.f, 0.f, 0.f, 0.f};

  const short8* wlds = (const short8*)s_wfrag;
#pragma unroll
  for (int s = 0; s < 4; ++s) {
#pragma unroll
    for (int t = 0; t < 8; ++t) {
      const short8 av = wlds[(s * 8 + t) * 64 + lane];
      acc[0][t] = __builtin_amdgcn_mfma_f32_16x16x32_bf16(av, bv[0][s], acc[0][t], 0, 0, 0);
      acc[1][t] = __builtin_amdgcn_mfma_f32_16x16x32_bf16(av, bv[1][s], acc[1][t], 0, 0, 0);
    }
  }

  // Epilogue: two j-halves (th), wave-private transpose buffer.
  // acc[g][t][r] -> node row g*16+c, j = t*16 + q*4 + r.
  unsigned short* tr = &s_tr[wv][0];
#pragma unroll
  for (int th = 0; th < 2; ++th) {
#pragma unroll
    for (int g = 0; g < 2; ++g) {
#pragma unroll
      for (int tt = 0; tt < 4; ++tt) {
        const int t = th * 4 + tt;
        short4v p;
        p[0] = (short)f2bf(acc[g][t][0]); p[1] = (short)f2bf(acc[g][t][1]);
        p[2] = (short)f2bf(acc[g][t][2]); p[3] = (short)f2bf(acc[g][t][3]);
        *(short4v*)&tr[(g * 16 + c) * TRS + tt * 16 + q * 4] = p;
      }
    }
    // read back + store: 4 uint4/lane, 8 rows x 128 B contiguous per instr
#pragma unroll
    for (int jj = 0; jj < 4; ++jj) {
      const int chunk = jj * 64 + lane;       // 16 B chunks, 256 total
      const int row = chunk >> 3;             // node row 0..31
      const int co  = chunk & 7;              // chunk within 128 B half-row
      const uint4 v = *(const uint4*)&tr[row * TRS + co * 8];
      *(uint4*)(nf + (size_t)(m0 + row) * JDIM + th * 64 + co * 8) = v;
    }
  }
}

// ---------------------------------------------------------------------------
// Kernel B (round 9 REGIME CHANGE): 256 B-granule gathers.
// Old structure issued 16 independent random 64 B requests per wave-instr
// (measured 2.86 TB/s, occupancy-invariant -> request-rate ceiling, not
// byte ceiling). New: one wave = 4 edges x 16 lanes; each edge's full
// 256 B nf row is ONE fully-coalesced load instruction (4 requests/instr,
// 4x fewer requests for the same bytes).
// Lane = 16*es + j:  chunk j -> k = j>>2, feature slice m = j&3.
// Per node (16 edges = 4 passes): lane accumulates w[e,k] * chunk;
// butterfly shfl_xor over masks {4,8,16,32} sums over k and edge slot;
// lanes 0..7 store the 128 B output row. No LDS; ~45 VGPR -> full occupancy.
// ---------------------------------------------------------------------------
__global__ __launch_bounds__(256) void gmm_edge_gather(
    const int* __restrict__ rowptr, const int* __restrict__ colind,
    const int* __restrict__ permute, const float* __restrict__ pseudo,
    const float* __restrict__ mu, const float* __restrict__ inv_sigma,
    const float* __restrict__ bias, const unsigned short* __restrict__ nf,
    float* __restrict__ out)
{
  const int tid  = threadIdx.x;
  const int lane = tid & 63;
  const int gw   = blockIdx.x * 4 + (tid >> 6);   // global wave id
  const int NW   = gridDim.x * 4;

  const int es = lane >> 4;         // edge slot 0..3
  const int j  = lane & 15;         // 16 B chunk of the 256 B nf row
  const int k  = (lane >> 2) & 3;   // gaussian index (= j>>2)
  const int m  = lane & 3;          // feature slice (= j&3)
  const int h  = (lane >> 2) & 1;   // output half for the epilogue store

  // per-lane gaussian constants: only its own k
  const float mxk = mu[k * 2 + 0];
  const float myk = mu[k * 2 + 1];
  const float sxk = inv_sigma[k * 2 + 0];
  const float syk = inv_sigma[k * 2 + 1];
  // epilogue bias slice (valid offset for every lane; used by lanes < 8)
  const float4 b4 = *(const float4*)&bias[m * 8 + h * 4];

  for (int n = gw; n < NN; n += NW) {
    const int eb = rowptr[n];
    float acc[8];
#pragma unroll
    for (int t = 0; t < 8; ++t) acc[t] = 0.f;

#pragma unroll
    for (int p = 0; p < 4; ++p) {
      const int e  = eb + p * 4 + es;
      const int pe = permute[e];
      const int src = colind[e];
      const float2 pp = *(const float2*)&pseudo[(size_t)pe * 2];
      const float dx = (pp.x - mxk) * sxk;
      const float dy = (pp.y - myk) * syk;
      const float w  = __expf(-0.5f * (dx * dx + dy * dy));
      const uint4 v = *(const uint4*)(nf + (size_t)src * JDIM + j * 8);
      acc[0] += w * __uint_as_float(v.x << 16);
      acc[1] += w * __uint_as_float(v.x & 0xffff0000u);
      acc[2] += w * __uint_as_float(v.y << 16);
      acc[3] += w * __uint_as_float(v.y & 0xffff0000u);
      acc[4] += w * __uint_as_float(v.z << 16);
      acc[5] += w * __uint_as_float(v.z & 0xffff0000u);
      acc[6] += w * __uint_as_float(v.w << 16);
      acc[7] += w * __uint_as_float(v.w & 0xffff0000u);
    }

    // sum over k (lane bits 2,3) and edge slot (lane bits 4,5)
#pragma unroll
    for (int mask = 4; mask <= 32; mask <<= 1) {
#pragma unroll
      for (int t = 0; t < 8; ++t)
        acc[t] += __shfl_xor(acc[t], mask, 64);
    }

    // lanes 0..7 hold finished slices; lane l -> floats m*8 + h*4 .. +3
    if (lane < 8) {
      float4 o;
      o.x = acc[h * 4 + 0] + b4.x;
      o.y = acc[h * 4 + 1] + b4.y;
      o.z = acc[h * 4 + 2] + b4.z;
      o.w = acc[h * 4 + 3] + b4.w;
      *(float4*)(out + (size_t)n * OUT_F + m * 8 + h * 4) = o;
    }
  }
}

extern "C" void kernel_launch(void* const* d_in, const int* in_sizes, int n_in,
                              void* d_out, int out_size, void* d_ws, size_t ws_size,
                              hipStream_t stream) {
  const int*   rowptr    = (const int*)d_in[0];
  const int*   colind    = (const int*)d_in[1];
  // d_in[2] colptr, d_in[3] rowind: backward-only, unused in fwd
  const int*   permute   = (const int*)d_in[4];
  const float* feat      = (const float*)d_in[5];
  const float* pseudo    = (const float*)d_in[6];
  const float* fc_w      = (const float*)d_in[7];
  const float* mu        = (const float*)d_in[8];
  const float* inv_sigma = (const float*)d_in[9];
  const float* bias      = (const float*)d_in[10];
  float* out = (float*)d_out;

  unsigned short* nf = (unsigned short*)d_ws;   // 25.6 MB bf16 node features

  // A: 3125 32-node tiles, 4 waves/block -> 782 blocks (P folded inline)
  gmm_fc_mfma<<<(NN / 32 + 3) / 4, 256, 0, stream>>>(feat, fc_w, nf);
  // B: 2048 blocks x 4 waves, grid-stride one node per wave-round
  gmm_edge_gather<<<2048, 256, 0, stream>>>(
      rowptr, colind, permute, pseudo, mu, inv_sigma, bias, nf, out);
}

// Round 4
// 196.765 us; speedup vs baseline: 1.7980x; 1.0320x over previous
//
#include <hip/hip_runtime.h>

#define NN     100000
#define DEG    16
#define IN_F   128
#define OUT_F  32
#define KK     4
#define JDIM   (KK * OUT_F)   // 128
#define TRS    70             // transpose-buffer row stride in shorts (pad vs 64)

typedef __attribute__((ext_vector_type(8))) short short8;     // 8 bf16 = 4 VGPR
typedef __attribute__((ext_vector_type(4))) short short4v;    // 4 bf16 = 8 B
typedef __attribute__((ext_vector_type(4))) float floatx4;    // MFMA C/D

// fp32 -> bf16 bits, round-to-nearest-even (inputs are finite normals)
static __device__ __forceinline__ unsigned short f2bf(float f) {
  unsigned int u = __builtin_bit_cast(unsigned int, f);
  u += 0x7fffu + ((u >> 16) & 1u);
  return (unsigned short)(u >> 16);
}

// ---------------------------------------------------------------------------
// Kernel A (MFMA), round-7 structure + W-conversion folded inline (round-3,
// verified): each block converts fc_w (fp32, 64 KB, L2-resident) -> bf16
// MFMA A-fragments directly into LDS. Slot g=(s*8+t)*64+q*16+c holds
// fc_w[t*16+c][s*32+q*8..+7]. One wave per 32-node tile, 4 waves/block,
// wave-private LDS-transpose epilogue -> 128 B-contiguous nf stores.
// LDS 49.5 KB -> 3 blocks/CU.
// ---------------------------------------------------------------------------
__global__ __launch_bounds__(256) void gmm_fc_mfma(
    const float* __restrict__ feat, const float* __restrict__ fc_w,
    unsigned short* __restrict__ nf)
{
  __shared__ uint4 s_wfrag[2048];                    // 32 KB
  __shared__ unsigned short s_tr[4][32 * TRS];       // 4 x 4.4 KB

  const int tid  = threadIdx.x;
  const int lane = tid & 63;
  const int wv   = tid >> 6;

  // inline W conversion: 8 fragment slots per thread, straight into LDS
#pragma unroll
  for (int r = 0; r < 8; ++r) {
    const int g = r * 256 + tid;                  // 0..2047
    const int c = g & 15, q = (g >> 4) & 3, t = (g >> 6) & 7, s = g >> 9;
    const float* src = fc_w + (size_t)(t * 16 + c) * IN_F + s * 32 + q * 8;
    const float4 f0 = *(const float4*)src;
    const float4 f1 = *(const float4*)(src + 4);
    short8 v;
    v[0] = (short)f2bf(f0.x); v[1] = (short)f2bf(f0.y);
    v[2] = (short)f2bf(f0.z); v[3] = (short)f2bf(f0.w);
    v[4] = (short)f2bf(f1.x); v[5] = (short)f2bf(f1.y);
    v[6] = (short)f2bf(f1.z); v[7] = (short)f2bf(f1.w);
    *(short8*)&s_wfrag[g] = v;
  }
  __syncthreads();

  const int tile = blockIdx.x * 4 + wv;            // 32-node tile id
  if (tile * 32 >= NN) return;                     // NN % 32 == 0: full tiles
  const int m0 = tile * 32;
  const int c  = lane & 15;
  const int q  = lane >> 4;

  // batch-load all feat inputs for this wave (16-deep MLP, one exposure)
  const float* frow0 = feat + (size_t)(m0 + c) * IN_F + q * 8;
  const float* frow1 = frow0 + (size_t)16 * IN_F;
  float4 fr[2][4][2];
#pragma unroll
  for (int s = 0; s < 4; ++s) {
    fr[0][s][0] = *(const float4*)(frow0 + s * 32);
    fr[0][s][1] = *(const float4*)(frow0 + s * 32 + 4);
    fr[1][s][0] = *(const float4*)(frow1 + s * 32);
    fr[1][s][1] = *(const float4*)(frow1 + s * 32 + 4);
  }

  // convert to bf16 B-fragments
  short8 bv[2][4];
#pragma unroll
  for (int g = 0; g < 2; ++g) {
#pragma unroll
    for (int s = 0; s < 4; ++s) {
      const float4 b0 = fr[g][s][0];
      const float4 b1 = fr[g][s][1];
      short8 v;
      v[0] = (short)f2bf(b0.x); v[1] = (short)f2bf(b0.y);
      v[2] = (short)f2bf(b0.z); v[3] = (short)f2bf(b0.w);
      v[4] = (short)f2bf(b1.x); v[5] = (short)f2bf(b1.y);
      v[6] = (short)f2bf(b1.z); v[7] = (short)f2bf(b1.w);
      bv[g][s] = v;
    }
  }

  floatx4 acc[2][8];
#pragma unroll
  for (int g = 0; g < 2; ++g)
#pragma unroll
    for (int t = 0; t < 8; ++t) acc[g][t] = (floatx4){0.f, 0.f, 0.f, 0.f};

  const short8* wlds = (const short8*)s_wfrag;
#pragma unroll
  for (int s = 0; s < 4; ++s) {
#pragma unroll
    for (int t = 0; t < 8; ++t) {
      const short8 av = wlds[(s * 8 + t) * 64 + lane];
      acc[0][t] = __builtin_amdgcn_mfma_f32_16x16x32_bf16(av, bv[0][s], acc[0][t], 0, 0, 0);
      acc[1][t] = __builtin_amdgcn_mfma_f32_16x16x32_bf16(av, bv[1][s], acc[1][t], 0, 0, 0);
    }
  }

  // Epilogue: two j-halves (th), wave-private transpose buffer.
  // acc[g][t][r] -> node row g*16+c, j = t*16 + q*4 + r.
  unsigned short* tr = &s_tr[wv][0];
#pragma unroll
  for (int th = 0; th < 2; ++th) {
#pragma unroll
    for (int g = 0; g < 2; ++g) {
#pragma unroll
      for (int tt = 0; tt < 4; ++tt) {
        const int t = th * 4 + tt;
        short4v p;
        p[0] = (short)f2bf(acc[g][t][0]); p[1] = (short)f2bf(acc[g][t][1]);
        p[2] = (short)f2bf(acc[g][t][2]); p[3] = (short)f2bf(acc[g][t][3]);
        *(short4v*)&tr[(g * 16 + c) * TRS + tt * 16 + q * 4] = p;
      }
    }
    // read back + store: 4 uint4/lane, 8 rows x 128 B contiguous per instr
#pragma unroll
    for (int jj = 0; jj < 4; ++jj) {
      const int chunk = jj * 64 + lane;       // 16 B chunks, 256 total
      const int row = chunk >> 3;             // node row 0..31
      const int co  = chunk & 7;              // chunk within 128 B half-row
      const uint4 v = *(const uint4*)&tr[row * TRS + co * 8];
      *(uint4*)(nf + (size_t)(m0 + row) * JDIM + th * 64 + co * 8) = v;
    }
  }
}

// ---------------------------------------------------------------------------
// Kernel B (round-0/round-3-of-prior-session VERBATIM — measured 63-65 µs at
// the ~3.2-3.4 TB/s fabric/L3 ceiling for random-64B gathers; invariant
// across occupancy 18/26/52% -> structural; round-3-this-session's 256B-
// granule variant regressed to 77 µs (same 64B L2 requests, 4x less MLP,
// +32 shuffles/node). Do not re-tune.)
// out[i][f] = bias[f] + sum_{e in row i} sum_k w[e,k]*nf[src_e][k*32+f]
// Block = 256 thr = 64 nodes x 4 lanes (8 features each, uint4 gathers,
// 4 lanes x 16B = 64B per (src,k)). 1024 edges staged in LDS.
// Edge read order rotated by local node id -> LDS bank-conflict-free.
// ---------------------------------------------------------------------------
__global__ __launch_bounds__(256) void gmm_edge_gather(
    const int* __restrict__ rowptr, const int* __restrict__ colind,
    const int* __restrict__ permute, const float* __restrict__ pseudo,
    const float* __restrict__ mu, const float* __restrict__ inv_sigma,
    const float* __restrict__ bias, const unsigned short* __restrict__ nf,
    float* __restrict__ out)
{
  __shared__ int   s_src[1024];      // 4 KB
  __shared__ float s_w[1024][4];     // 16 KB

  const int tid    = threadIdx.x;
  const int node0  = blockIdx.x * 64;
  const int nvalid = (NN - node0 < 64) ? (NN - node0) : 64;

  float mx[KK], my[KK], sx[KK], sy[KK];
#pragma unroll
  for (int k = 0; k < KK; ++k) {
    mx[k] = mu[k * 2 + 0];
    my[k] = mu[k * 2 + 1];
    sx[k] = inv_sigma[k * 2 + 0];
    sy[k] = inv_sigma[k * 2 + 1];
  }

  // stage 1024 edges (4 per thread): src id + 4 gaussian weights
#pragma unroll
  for (int r = 0; r < 4; ++r) {
    const int t  = tid + r * 256;
    const int nl = t >> 4;
    if (nl < nvalid) {
      const int e   = rowptr[node0 + nl] + (t & 15);
      const int pe  = permute[e];
      s_src[t] = colind[e];
      const float px = pseudo[(size_t)pe * 2 + 0];
      const float py = pseudo[(size_t)pe * 2 + 1];
#pragma unroll
      for (int k = 0; k < KK; ++k) {
        const float dx = (px - mx[k]) * sx[k];
        const float dy = (py - my[k]) * sy[k];
        s_w[t][k] = __expf(-0.5f * (dx * dx + dy * dy));
      }
    }
  }
  __syncthreads();

  const int nl = tid >> 2;    // local node 0..63
  const int f8 = tid & 3;     // features f8*8 .. f8*8+7
  if (nl >= nvalid) return;

  float acc[8];
  {
    const float4 b0 = *(const float4*)&bias[f8 * 8];
    const float4 b1 = *(const float4*)&bias[f8 * 8 + 4];
    acc[0] = b0.x; acc[1] = b0.y; acc[2] = b0.z; acc[3] = b0.w;
    acc[4] = b1.x; acc[5] = b1.y; acc[6] = b1.z; acc[7] = b1.w;
  }

  const int tbase = nl * 16;
#pragma unroll
  for (int i = 0; i < DEG; ++i) {
    const int e = (i + nl) & 15;          // rotate: conflict-free LDS reads
    const int t = tbase + e;
    const int src = s_src[t];
    const float4 w4 = *(const float4*)&s_w[t][0];
    const float wv[4] = {w4.x, w4.y, w4.z, w4.w};
    const unsigned short* row = nf + (size_t)src * JDIM + f8 * 8;
#pragma unroll
    for (int k = 0; k < KK; ++k) {
      const uint4 v = *(const uint4*)(row + k * 32);
      const float wk = wv[k];
      acc[0] += wk * __uint_as_float(v.x << 16);
      acc[1] += wk * __uint_as_float(v.x & 0xffff0000u);
      acc[2] += wk * __uint_as_float(v.y << 16);
      acc[3] += wk * __uint_as_float(v.y & 0xffff0000u);
      acc[4] += wk * __uint_as_float(v.z << 16);
      acc[5] += wk * __uint_as_float(v.z & 0xffff0000u);
      acc[6] += wk * __uint_as_float(v.w << 16);
      acc[7] += wk * __uint_as_float(v.w & 0xffff0000u);
    }
  }

  float4 o0 = {acc[0], acc[1], acc[2], acc[3]};
  float4 o1 = {acc[4], acc[5], acc[6], acc[7]};
  float* op = out + (size_t)(node0 + nl) * OUT_F + f8 * 8;
  *(float4*)(op)     = o0;
  *(float4*)(op + 4) = o1;
}

extern "C" void kernel_launch(void* const* d_in, const int* in_sizes, int n_in,
                              void* d_out, int out_size, void* d_ws, size_t ws_size,
                              hipStream_t stream) {
  const int*   rowptr    = (const int*)d_in[0];
  const int*   colind    = (const int*)d_in[1];
  // d_in[2] colptr, d_in[3] rowind: backward-only, unused in fwd
  const int*   permute   = (const int*)d_in[4];
  const float* feat      = (const float*)d_in[5];
  const float* pseudo    = (const float*)d_in[6];
  const float* fc_w      = (const float*)d_in[7];
  const float* mu        = (const float*)d_in[8];
  const float* inv_sigma = (const float*)d_in[9];
  const float* bias      = (const float*)d_in[10];
  float* out = (float*)d_out;

  unsigned short* nf = (unsigned short*)d_ws;   // 25.6 MB bf16 node features

  // A: 3125 32-node tiles, 4 waves/block -> 782 blocks (W-convert inline)
  gmm_fc_mfma<<<(NN / 32 + 3) / 4, 256, 0, stream>>>(feat, fc_w, nf);
  // B: 64 nodes/block -> 1563 blocks
  gmm_edge_gather<<<(NN + 63) / 64, 256, 0, stream>>>(
      rowptr, colind, permute, pseudo, mu, inv_sigma, bias, nf, out);
}

// Round 5
// 194.097 us; speedup vs baseline: 1.8227x; 1.0137x over previous
//
#include <hip/hip_runtime.h>

#define NN     100000
#define DEG    16
#define IN_F   128
#define OUT_F  32
#define KK     4
#define JDIM   (KK * OUT_F)   // 128
#define TRS    70             // transpose-buffer row stride in shorts (pad vs 64)

typedef __attribute__((ext_vector_type(8))) short short8;     // 8 bf16 = 4 VGPR
typedef __attribute__((ext_vector_type(4))) float floatx4;    // MFMA C/D
typedef __attribute__((ext_vector_type(4))) unsigned int uint4v;

// packed fp32x2 -> bf16x2 (RTNE), gfx950 hardware convert (T12 primitive).
// word = [bf16(hi)<<16 | bf16(lo)] -> little-endian shorts {lo, hi}.
static __device__ __forceinline__ unsigned int cvt_pk_bf16(float lo, float hi) {
  unsigned int r;
  asm("v_cvt_pk_bf16_f32 %0, %1, %2" : "=v"(r) : "v"(lo), "v"(hi));
  return r;
}

// ---------------------------------------------------------------------------
// Kernel A (MFMA), round-7 structure + inline W-conversion (round-3/4,
// verified) + round-5 change: ALL fp32->bf16 conversions via
// v_cvt_pk_bf16_f32 (2 elems/instr) instead of ~5-op scalar RTNE bit-twiddle.
// Theory: A was VALU-throttled (~800 conv VALU instr/thread vs 320 MFMA cyc);
// packed converts cut that ~10x, moving A toward its 12.8 us byte-roofline.
// Layout facts unchanged: s_wfrag slot g=(s*8+t)*64+q*16+c holds
// fc_w[t*16+c][s*32+q*8..+7]; one wave per 32-node tile, 4 waves/block;
// wave-private LDS-transpose epilogue -> 128 B-contiguous nf stores.
// LDS 49.5 KB -> 3 blocks/CU.
// ---------------------------------------------------------------------------
__global__ __launch_bounds__(256) void gmm_fc_mfma(
    const float* __restrict__ feat, const float* __restrict__ fc_w,
    unsigned short* __restrict__ nf)
{
  __shared__ uint4 s_wfrag[2048];                    // 32 KB
  __shared__ unsigned short s_tr[4][32 * TRS];       // 4 x 4.4 KB

  const int tid  = threadIdx.x;
  const int lane = tid & 63;
  const int wv   = tid >> 6;

  // inline W conversion: 8 fragment slots per thread, packed converts
#pragma unroll
  for (int r = 0; r < 8; ++r) {
    const int g = r * 256 + tid;                  // 0..2047
    const int c = g & 15, q = (g >> 4) & 3, t = (g >> 6) & 7, s = g >> 9;
    const float* src = fc_w + (size_t)(t * 16 + c) * IN_F + s * 32 + q * 8;
    const float4 f0 = *(const float4*)src;
    const float4 f1 = *(const float4*)(src + 4);
    uint4 v;
    v.x = cvt_pk_bf16(f0.x, f0.y);
    v.y = cvt_pk_bf16(f0.z, f0.w);
    v.z = cvt_pk_bf16(f1.x, f1.y);
    v.w = cvt_pk_bf16(f1.z, f1.w);
    s_wfrag[g] = v;
  }
  __syncthreads();

  const int tile = blockIdx.x * 4 + wv;            // 32-node tile id
  if (tile * 32 >= NN) return;                     // NN % 32 == 0: full tiles
  const int m0 = tile * 32;
  const int c  = lane & 15;
  const int q  = lane >> 4;

  // batch-load all feat inputs for this wave (16-deep MLP, one exposure)
  const float* frow0 = feat + (size_t)(m0 + c) * IN_F + q * 8;
  const float* frow1 = frow0 + (size_t)16 * IN_F;
  float4 fr[2][4][2];
#pragma unroll
  for (int s = 0; s < 4; ++s) {
    fr[0][s][0] = *(const float4*)(frow0 + s * 32);
    fr[0][s][1] = *(const float4*)(frow0 + s * 32 + 4);
    fr[1][s][0] = *(const float4*)(frow1 + s * 32);
    fr[1][s][1] = *(const float4*)(frow1 + s * 32 + 4);
  }

  // convert to bf16 B-fragments (packed)
  short8 bv[2][4];
#pragma unroll
  for (int g = 0; g < 2; ++g) {
#pragma unroll
    for (int s = 0; s < 4; ++s) {
      const float4 b0 = fr[g][s][0];
      const float4 b1 = fr[g][s][1];
      uint4v uv;
      uv[0] = cvt_pk_bf16(b0.x, b0.y);
      uv[1] = cvt_pk_bf16(b0.z, b0.w);
      uv[2] = cvt_pk_bf16(b1.x, b1.y);
      uv[3] = cvt_pk_bf16(b1.z, b1.w);
      bv[g][s] = __builtin_bit_cast(short8, uv);
    }
  }

  floatx4 acc[2][8];
#pragma unroll
  for (int g = 0; g < 2; ++g)
#pragma unroll
    for (int t = 0; t < 8; ++t) acc[g][t] = (floatx4){0.f, 0.f, 0.f, 0.f};

  const short8* wlds = (const short8*)s_wfrag;
#pragma unroll
  for (int s = 0; s < 4; ++s) {
#pragma unroll
    for (int t = 0; t < 8; ++t) {
      const short8 av = wlds[(s * 8 + t) * 64 + lane];
      acc[0][t] = __builtin_amdgcn_mfma_f32_16x16x32_bf16(av, bv[0][s], acc[0][t], 0, 0, 0);
      acc[1][t] = __builtin_amdgcn_mfma_f32_16x16x32_bf16(av, bv[1][s], acc[1][t], 0, 0, 0);
    }
  }

  // Epilogue: two j-halves (th), wave-private transpose buffer.
  // acc[g][t][r] -> node row g*16+c, j = t*16 + q*4 + r.
  // Packed converts: 2 x 32-bit LDS stores (4 B-aligned: all index terms even).
  unsigned short* tr = &s_tr[wv][0];
#pragma unroll
  for (int th = 0; th < 2; ++th) {
#pragma unroll
    for (int g = 0; g < 2; ++g) {
#pragma unroll
      for (int tt = 0; tt < 4; ++tt) {
        const int t = th * 4 + tt;
        unsigned int* d = (unsigned int*)&tr[(g * 16 + c) * TRS + tt * 16 + q * 4];
        d[0] = cvt_pk_bf16(acc[g][t][0], acc[g][t][1]);
        d[1] = cvt_pk_bf16(acc[g][t][2], acc[g][t][3]);
      }
    }
    // read back + store: 4 uint4/lane, 8 rows x 128 B contiguous per instr
#pragma unroll
    for (int jj = 0; jj < 4; ++jj) {
      const int chunk = jj * 64 + lane;       // 16 B chunks, 256 total
      const int row = chunk >> 3;             // node row 0..31
      const int co  = chunk & 7;              // chunk within 128 B half-row
      const uint4 v = *(const uint4*)&tr[row * TRS + co * 8];
      *(uint4*)(nf + (size_t)(m0 + row) * JDIM + th * 64 + co * 8) = v;
    }
  }
}

// ---------------------------------------------------------------------------
// Kernel B (VERBATIM — measured 63-66 µs at the ~3.1 TB/s fabric/L3 ceiling
// for random-64B gathers; occupancy-invariant 18/26/52% -> structural; the
// 256B-granule variant regressed to 77 µs. Do not re-tune.)
// out[i][f] = bias[f] + sum_{e in row i} sum_k w[e,k]*nf[src_e][k*32+f]
// Block = 256 thr = 64 nodes x 4 lanes (8 features each, uint4 gathers,
// 4 lanes x 16B = 64B per (src,k)). 1024 edges staged in LDS.
// Edge read order rotated by local node id -> LDS bank-conflict-free.
// ---------------------------------------------------------------------------
__global__ __launch_bounds__(256) void gmm_edge_gather(
    const int* __restrict__ rowptr, const int* __restrict__ colind,
    const int* __restrict__ permute, const float* __restrict__ pseudo,
    const float* __restrict__ mu, const float* __restrict__ inv_sigma,
    const float* __restrict__ bias, const unsigned short* __restrict__ nf,
    float* __restrict__ out)
{
  __shared__ int   s_src[1024];      // 4 KB
  __shared__ float s_w[1024][4];     // 16 KB

  const int tid    = threadIdx.x;
  const int node0  = blockIdx.x * 64;
  const int nvalid = (NN - node0 < 64) ? (NN - node0) : 64;

  float mx[KK], my[KK], sx[KK], sy[KK];
#pragma unroll
  for (int k = 0; k < KK; ++k) {
    mx[k] = mu[k * 2 + 0];
    my[k] = mu[k * 2 + 1];
    sx[k] = inv_sigma[k * 2 + 0];
    sy[k] = inv_sigma[k * 2 + 1];
  }

  // stage 1024 edges (4 per thread): src id + 4 gaussian weights
#pragma unroll
  for (int r = 0; r < 4; ++r) {
    const int t  = tid + r * 256;
    const int nl = t >> 4;
    if (nl < nvalid) {
      const int e   = rowptr[node0 + nl] + (t & 15);
      const int pe  = permute[e];
      s_src[t] = colind[e];
      const float px = pseudo[(size_t)pe * 2 + 0];
      const float py = pseudo[(size_t)pe * 2 + 1];
#pragma unroll
      for (int k = 0; k < KK; ++k) {
        const float dx = (px - mx[k]) * sx[k];
        const float dy = (py - my[k]) * sy[k];
        s_w[t][k] = __expf(-0.5f * (dx * dx + dy * dy));
      }
    }
  }
  __syncthreads();

  const int nl = tid >> 2;    // local node 0..63
  const int f8 = tid & 3;     // features f8*8 .. f8*8+7
  if (nl >= nvalid) return;

  float acc[8];
  {
    const float4 b0 = *(const float4*)&bias[f8 * 8];
    const float4 b1 = *(const float4*)&bias[f8 * 8 + 4];
    acc[0] = b0.x; acc[1] = b0.y; acc[2] = b0.z; acc[3] = b0.w;
    acc[4] = b1.x; acc[5] = b1.y; acc[6] = b1.z; acc[7] = b1.w;
  }

  const int tbase = nl * 16;
#pragma unroll
  for (int i = 0; i < DEG; ++i) {
    const int e = (i + nl) & 15;          // rotate: conflict-free LDS reads
    const int t = tbase + e;
    const int src = s_src[t];
    const float4 w4 = *(const float4*)&s_w[t][0];
    const float wv[4] = {w4.x, w4.y, w4.z, w4.w};
    const unsigned short* row = nf + (size_t)src * JDIM + f8 * 8;
#pragma unroll
    for (int k = 0; k < KK; ++k) {
      const uint4 v = *(const uint4*)(row + k * 32);
      const float wk = wv[k];
      acc[0] += wk * __uint_as_float(v.x << 16);
      acc[1] += wk * __uint_as_float(v.x & 0xffff0000u);
      acc[2] += wk * __uint_as_float(v.y << 16);
      acc[3] += wk * __uint_as_float(v.y & 0xffff0000u);
      acc[4] += wk * __uint_as_float(v.z << 16);
      acc[5] += wk * __uint_as_float(v.z & 0xffff0000u);
      acc[6] += wk * __uint_as_float(v.w << 16);
      acc[7] += wk * __uint_as_float(v.w & 0xffff0000u);
    }
  }

  float4 o0 = {acc[0], acc[1], acc[2], acc[3]};
  float4 o1 = {acc[4], acc[5], acc[6], acc[7]};
  float* op = out + (size_t)(node0 + nl) * OUT_F + f8 * 8;
  *(float4*)(op)     = o0;
  *(float4*)(op + 4) = o1;
}

extern "C" void kernel_launch(void* const* d_in, const int* in_sizes, int n_in,
                              void* d_out, int out_size, void* d_ws, size_t ws_size,
                              hipStream_t stream) {
  const int*   rowptr    = (const int*)d_in[0];
  const int*   colind    = (const int*)d_in[1];
  // d_in[2] colptr, d_in[3] rowind: backward-only, unused in fwd
  const int*   permute   = (const int*)d_in[4];
  const float* feat      = (const float*)d_in[5];
  const float* pseudo    = (const float*)d_in[6];
  const float* fc_w      = (const float*)d_in[7];
  const float* mu        = (const float*)d_in[8];
  const float* inv_sigma = (const float*)d_in[9];
  const float* bias      = (const float*)d_in[10];
  float* out = (float*)d_out;

  unsigned short* nf = (unsigned short*)d_ws;   // 25.6 MB bf16 node features

  // A: 3125 32-node tiles, 4 waves/block -> 782 blocks (W-convert inline)
  gmm_fc_mfma<<<(NN / 32 + 3) / 4, 256, 0, stream>>>(feat, fc_w, nf);
  // B: 64 nodes/block -> 1563 blocks
  gmm_edge_gather<<<(NN + 63) / 64, 256, 0, stream>>>(
      rowptr, colind, permute, pseudo, mu, inv_sigma, bias, nf, out);
}